// Round 10
// baseline (540.808 us; speedup 1.0000x reference)
//
#include <hip/hip_runtime.h>
#include <cstdint>

#define NN 20000
#define EE 320000
#define DHID 256

typedef short bf16x8 __attribute__((ext_vector_type(8)));
typedef float f32x4 __attribute__((ext_vector_type(4)));

// ---------------------------------------------------------------- utilities

__device__ __forceinline__ float b2f(unsigned short u) {
    union { unsigned int i; float f; } v;
    v.i = ((unsigned int)u) << 16;
    return v.f;
}

__device__ __forceinline__ void b2f2(unsigned int w, float& lo, float& hi) {
    union { unsigned int i; float f; } a, c;
    a.i = w << 16;
    c.i = w & 0xffff0000u;
    lo = a.f;
    hi = c.f;
}

__device__ __forceinline__ unsigned short f2b(float x) {
    union { float f; unsigned int i; } v;
    v.f = x;
    unsigned int r = (v.i + 0x7FFFu + ((v.i >> 16) & 1u)) >> 16;
    return (unsigned short)r;
}

__device__ __forceinline__ float wave_sum(float v) {
#pragma unroll
    for (int m = 1; m < 64; m <<= 1) v += __shfl_xor(v, m);
    return v;
}

// 16-lane full sum via DPP row rotations (pure VALU, no LDS/bpermute ops).
#define DPP_ROR_ADD(v, n)                                                                  \
    v += __int_as_float(__builtin_amdgcn_update_dpp(__float_as_int(v), __float_as_int(v),  \
                                                    0x120 + (n), 0xF, 0xF, 0))
__device__ __forceinline__ float quad16_sum(float v) {
    DPP_ROR_ADD(v, 8);
    DPP_ROR_ADD(v, 4);
    DPP_ROR_ADD(v, 2);
    DPP_ROR_ADD(v, 1);
    return v;
}

// gelu tanh-approx, algebra-reduced: gelu = x*(1 - 1/(e+1)), e = exp(2z).
__device__ __forceinline__ float gelu_f(float x) {
    float x2 = x * x;
    float p  = fmaf(0.044715f, x2, 1.0f);
    float e  = __expf(x * p * 1.5957691216f);   // exp(2z)
    float r  = 1.0f / (e + 1.0f);
    return x - x * r;
}

// async global->LDS, 16B per lane; lds dest is wave-uniform base (+HW lane*16)
__device__ __forceinline__ void gld16(const unsigned short* g, unsigned short* lds) {
    __builtin_amdgcn_global_load_lds((const __attribute__((address_space(1))) unsigned int*)g,
                                     (__attribute__((address_space(3))) unsigned int*)lds, 16, 0, 0);
}

// ---------------------------------------------------------------- CSR build (4-aligned, padded, byte offsets)

__global__ void hist_kernel(const int* __restrict__ edges, int* __restrict__ counts, int E_) {
    int e = blockIdx.x * 256 + threadIdx.x;
    if (e >= E_) return;
    atomicAdd(&counts[edges[e * 2]], 1);
}

// scan over PADDED counts ((c+3)&~3), padding folded in here
__global__ __launch_bounds__(1024) void scan_block(const int* __restrict__ counts,
                                                   int* __restrict__ excl,
                                                   int* __restrict__ bsums, int n) {
    __shared__ int sd[1024];
    int tid = threadIdx.x;
    int i = blockIdx.x * 1024 + tid;
    int c = (i < n) ? ((counts[i] + 3) & ~3) : 0;
    sd[tid] = c;
    __syncthreads();
#pragma unroll
    for (int off = 1; off < 1024; off <<= 1) {
        int v = (tid >= off) ? sd[tid - off] : 0;
        __syncthreads();
        sd[tid] += v;
        __syncthreads();
    }
    if (i < n) excl[i] = sd[tid] - c;
    if (tid == 1023) bsums[blockIdx.x] = sd[1023];
}

// astart (aligned start), aend = astart + true degree, cursor = astart.
// bsums holds RAW per-block sums; prefix over <=20 entries computed inline.
__global__ void scan_fix2(const int* __restrict__ excl, const int* __restrict__ bsums,
                          const int* __restrict__ counts,
                          int* __restrict__ astart, int* __restrict__ aend,
                          int* __restrict__ cursor, int n) {
    int i = blockIdx.x * 256 + threadIdx.x;
    if (i < n) {
        int blk = i >> 10;
        int base = 0;
        for (int j = 0; j < blk; ++j) base += bsums[j];
        int v = excl[i] + base;
        astart[i] = v;
        cursor[i] = v;
        aend[i]   = v + counts[i];
    }
}

__global__ void scatter2(const int* __restrict__ edges, int* __restrict__ cursor,
                         unsigned int* __restrict__ soff, int E_) {
    int e = blockIdx.x * 256 + threadIdx.x;
    if (e >= E_) return;
    int dstn = edges[e * 2];
    int src  = edges[e * 2 + 1];
    int pos = atomicAdd(&cursor[dstn], 1);
    soff[pos] = (unsigned int)src << 10;   // byte offset into zr (512 shorts/row)
}

// ---------------------------------------------------------------- weight transpose: W (K x M) fp32 -> Wt (M x K) bf16

__global__ __launch_bounds__(256) void transpose_bf16(const float* __restrict__ W,
                                                      unsigned short* __restrict__ Wt,
                                                      int K, int M, size_t lsW, size_t lsT) {
    W  += (size_t)blockIdx.z * lsW;
    Wt += (size_t)blockIdx.z * lsT;
    __shared__ float sm[32][33];
    int m0 = blockIdx.x * 32, k0 = blockIdx.y * 32;
    int tx = threadIdx.x & 31, ty = threadIdx.x >> 5;
#pragma unroll
    for (int i = 0; i < 4; ++i)
        sm[ty + i * 8][tx] = W[(size_t)(k0 + ty + i * 8) * M + m0 + tx];
    __syncthreads();
#pragma unroll
    for (int i = 0; i < 4; ++i)
        Wt[(size_t)(m0 + ty + i * 8) * K + k0 + tx] = f2b(sm[tx][ty + i * 8]);
}

// dense_W variant: column m = c*256 + j (c = chunk, j = feature) mapped to row
// cc = (by<<7)|((t>>4)<<6)|(c<<4)|(t&15) with by = j>>5, t = j&31, so that in the
// 128x128 GEMM tile a feature's 4 chunks land in ONE thread's 4 ni accumulators.
__global__ __launch_bounds__(256) void transpose_perm(const float* __restrict__ W,
                                                      unsigned short* __restrict__ Wt,
                                                      int K, int M, size_t lsW, size_t lsT) {
    W  += (size_t)blockIdx.z * lsW;
    Wt += (size_t)blockIdx.z * lsT;
    __shared__ float sm[32][33];
    int m0 = blockIdx.x * 32, k0 = blockIdx.y * 32;
    int tx = threadIdx.x & 31, ty = threadIdx.x >> 5;
#pragma unroll
    for (int i = 0; i < 4; ++i)
        sm[ty + i * 8][tx] = W[(size_t)(k0 + ty + i * 8) * M + m0 + tx];
    __syncthreads();
#pragma unroll
    for (int i = 0; i < 4; ++i) {
        int mm = m0 + ty + i * 8;
        int c = mm >> 8, j = mm & 255;
        int by = j >> 5, t = j & 31;
        int cc = (by << 7) | ((t >> 4) << 6) | (c << 4) | (t & 15);
        Wt[(size_t)cc * K + k0 + tx] = f2b(sm[tx][ty + i * 8]);
    }
}

__global__ void convert_bf16(const float* __restrict__ in, unsigned short* __restrict__ out, int n4) {
    int i = blockIdx.x * 256 + threadIdx.x;
    if (i >= n4) return;
    float4 v = *(const float4*)(in + (size_t)i * 4);
    ushort4 o;
    o.x = f2b(v.x); o.y = f2b(v.y); o.z = f2b(v.z); o.w = f2b(v.w);
    *(ushort4*)(out + (size_t)i * 4) = o;
}

// ---------------------------------------------------------------- LayerNorm (fp32 in -> bf16 out only)

__global__ __launch_bounds__(256) void ln_kernel(const float* __restrict__ X,
                                                 const float* __restrict__ g,
                                                 const float* __restrict__ b,
                                                 unsigned short* __restrict__ Yb, int nrows) {
    int row = blockIdx.x * 4 + (threadIdx.x >> 6);
    int lane = threadIdx.x & 63;
    if (row >= nrows) return;
    float4 v = *(const float4*)(X + (size_t)row * DHID + lane * 4);
    float sum = wave_sum(v.x + v.y + v.z + v.w);
    float sq  = wave_sum(v.x * v.x + v.y * v.y + v.z * v.z + v.w * v.w);
    float mean = sum * (1.0f / DHID);
    float var  = sq * (1.0f / DHID) - mean * mean;
    float r = rsqrtf(fmaxf(var, 0.0f) + 1e-3f);
    float4 gv = *(const float4*)(g + lane * 4);
    float4 bv = *(const float4*)(b + lane * 4);
    float4 o;
    o.x = (v.x - mean) * r * gv.x + bv.x;
    o.y = (v.y - mean) * r * gv.y + bv.y;
    o.z = (v.z - mean) * r * gv.z + bv.z;
    o.w = (v.w - mean) * r * gv.w + bv.w;
    ushort4 ob;
    ob.x = f2b(o.x); ob.y = f2b(o.y); ob.z = f2b(o.z); ob.w = f2b(o.w);
    *(ushort4*)(Yb + (size_t)row * DHID + lane * 4) = ob;
}

// LayerNorm over (dense-sum d + residual xrb), both bf16 N x 256
__global__ __launch_bounds__(256) void ln_dense(const unsigned short* __restrict__ d,
                                                const unsigned short* __restrict__ xrb,
                                                const float* __restrict__ g,
                                                const float* __restrict__ b,
                                                unsigned short* __restrict__ Yb, int nrows) {
    int row = blockIdx.x * 4 + (threadIdx.x >> 6);
    int lane = threadIdx.x & 63;
    if (row >= nrows) return;
    ushort4 xu = *(const ushort4*)(xrb + (size_t)row * DHID + lane * 4);
    ushort4 du = *(const ushort4*)(d   + (size_t)row * DHID + lane * 4);
    float4 v;
    v.x = b2f(xu.x) + b2f(du.x);
    v.y = b2f(xu.y) + b2f(du.y);
    v.z = b2f(xu.z) + b2f(du.z);
    v.w = b2f(xu.w) + b2f(du.w);
    float sum = wave_sum(v.x + v.y + v.z + v.w);
    float sq  = wave_sum(v.x * v.x + v.y * v.y + v.z * v.z + v.w * v.w);
    float mean = sum * (1.0f / DHID);
    float var  = sq * (1.0f / DHID) - mean * mean;
    float r = rsqrtf(fmaxf(var, 0.0f) + 1e-3f);
    float4 gv = *(const float4*)(g + lane * 4);
    float4 bv = *(const float4*)(b + lane * 4);
    float4 o;
    o.x = (v.x - mean) * r * gv.x + bv.x;
    o.y = (v.y - mean) * r * gv.y + bv.y;
    o.z = (v.z - mean) * r * gv.z + bv.z;
    o.w = (v.w - mean) * r * gv.w + bv.w;
    ushort4 ob;
    ob.x = f2b(o.x); ob.y = f2b(o.y); ob.z = f2b(o.z); ob.w = f2b(o.w);
    *(ushort4*)(Yb + (size_t)row * DHID + lane * 4) = ob;
}

// final combine (no LN): hb = bf16(d + xrb)
__global__ __launch_bounds__(256) void combine_final(const unsigned short* __restrict__ d,
                                                     const unsigned short* __restrict__ xrb,
                                                     unsigned short* __restrict__ hb, int nrows) {
    int row = blockIdx.x * 4 + (threadIdx.x >> 6);
    int lane = threadIdx.x & 63;
    if (row >= nrows) return;
    ushort4 xu = *(const ushort4*)(xrb + (size_t)row * DHID + lane * 4);
    ushort4 du = *(const ushort4*)(d   + (size_t)row * DHID + lane * 4);
    ushort4 ob;
    ob.x = f2b(b2f(xu.x) + b2f(du.x));
    ob.y = f2b(b2f(xu.y) + b2f(du.y));
    ob.z = f2b(b2f(xu.z) + b2f(du.z));
    ob.w = f2b(b2f(xu.w) + b2f(du.w));
    *(ushort4*)(hb + (size_t)row * DHID + lane * 4) = ob;
}

// ---------------------------------------------------------------- MFMA GEMM, 128x128 tile, BK=64
// A: nrows x 256 bf16 (k contig); B: ncols x 256 bf16 (k contig, i.e. W^T)
// EP: 0 = fp32 out (+bias), 1 = bf16 out,
//     3 = chunk-folded dense (B rows permuted so a feature's 4 chunks sit in one
//         thread's 4 ni accs): out[row][jf] = sum_ni gelu(acc[mi][ni][r]+bias) — no shuffles
// Grid-x padded to multiple of 8 -> XCD = bx & 7 for all by (A fetched once).
// R10: __launch_bounds__(256,4) -> 4 blocks/CU (LDS 4x35840=143KB fits 160KB;
// VGPR 64 allows it); latency-bound staging gets a 4th overlapping block.

#define CS_STRIDE 140   // 128 + 12 shorts (EP1 staging)
#define CS2_STRIDE 40   // 32 + 8 shorts (EP3 staging; 80B rows keep 16B alignment)

template <int EP>
__global__ __launch_bounds__(256, 4) void gemm128(const unsigned short* __restrict__ A,
                                                  const unsigned short* __restrict__ B,
                                                  const float* __restrict__ bias,
                                                  void* __restrict__ Cv, int nrows, int ncols) {
    __shared__ unsigned short smem[128 * CS_STRIDE];  // 35840 B; >= As(16KB)+Bs(16KB)
    unsigned short* As = smem;                        // 8192 shorts (128 rows x 64 k)
    unsigned short* Bs = smem + 8192;                 // 8192 shorts (128 cols x 64 k)
    unsigned short* Cs = smem;                        // epilogue alias (after final barrier)
    const int bm = blockIdx.x * 128, bn = blockIdx.y * 128;
    if (bm >= nrows) return;  // grid-x padding
    const int tid  = threadIdx.x;
    const int w    = tid >> 6, lane = tid & 63;
    const int quad = lane >> 4, l16 = lane & 15;
    const int wm = w >> 1, wn = w & 1;

    const int srow = lane & 15;
    const int sg   = lane >> 4;   // 0..3
    int ga0 = min(bm + w * 32 + srow,      nrows - 1);
    int ga1 = min(bm + w * 32 + 16 + srow, nrows - 1);
    int gb0 = min(bn + w * 32 + srow,      ncols - 1);
    int gb1 = min(bn + w * 32 + 16 + srow, ncols - 1);
    const unsigned short* Ap0 = A + (size_t)ga0 * 256 + sg * 8;
    const unsigned short* Ap1 = A + (size_t)ga1 * 256 + sg * 8;
    const unsigned short* Bp0 = B + (size_t)gb0 * 256 + sg * 8;
    const unsigned short* Bp1 = B + (size_t)gb1 * 256 + sg * 8;
    unsigned short* la0 = As + (2 * w) * 1024;
    unsigned short* la1 = As + (2 * w + 1) * 1024;
    unsigned short* lb0 = Bs + (2 * w) * 1024;
    unsigned short* lb1 = Bs + (2 * w + 1) * 1024;

    f32x4 acc[4][4] = {};
    for (int k0 = 0; k0 < 256; k0 += 64) {
        gld16(Ap0 + k0,      la0);
        gld16(Ap0 + k0 + 32, la0 + 512);
        gld16(Ap1 + k0,      la1);
        gld16(Ap1 + k0 + 32, la1 + 512);
        gld16(Bp0 + k0,      lb0);
        gld16(Bp0 + k0 + 32, lb0 + 512);
        gld16(Bp1 + k0,      lb1);
        gld16(Bp1 + k0 + 32, lb1 + 512);
        __syncthreads();
#pragma unroll
        for (int kk = 0; kk < 2; ++kk) {
            bf16x8 a[4], b[4];
#pragma unroll
            for (int mi = 0; mi < 4; ++mi)
                a[mi] = *(const bf16x8*)(As + (wm * 4 + mi) * 1024 + (kk * 4 + quad) * 128 + l16 * 8);
#pragma unroll
            for (int ni = 0; ni < 4; ++ni)
                b[ni] = *(const bf16x8*)(Bs + (wn * 4 + ni) * 1024 + (kk * 4 + quad) * 128 + l16 * 8);
#pragma unroll
            for (int mi = 0; mi < 4; ++mi)
#pragma unroll
                for (int ni = 0; ni < 4; ++ni)
                    acc[mi][ni] = __builtin_amdgcn_mfma_f32_16x16x32_bf16(a[mi], b[ni], acc[mi][ni], 0, 0, 0);
        }
        __syncthreads();
    }

    if (EP == 0) {
        // fp32 out (head/tail): direct stores
#pragma unroll
        for (int ni = 0; ni < 4; ++ni) {
            int col = bn + wn * 64 + ni * 16 + l16;
            if (col >= ncols) continue;
            float bv = bias ? bias[col] : 0.0f;
#pragma unroll
            for (int mi = 0; mi < 4; ++mi) {
#pragma unroll
                for (int r = 0; r < 4; ++r) {
                    int row = bm + wm * 64 + mi * 16 + quad * 4 + r;
                    if (row < nrows) ((float*)Cv)[(size_t)row * ncols + col] = acc[mi][ni][r] + bv;
                }
            }
        }
    } else if (EP == 1) {
        // bf16 out: stage tile in Cs, coalesced 16B stores
#pragma unroll
        for (int ni = 0; ni < 4; ++ni) {
            int lc = wn * 64 + ni * 16 + l16;
#pragma unroll
            for (int mi = 0; mi < 4; ++mi) {
#pragma unroll
                for (int r = 0; r < 4; ++r) {
                    int lr = wm * 64 + mi * 16 + quad * 4 + r;
                    Cs[lr * CS_STRIDE + lc] = f2b(acc[mi][ni][r]);
                }
            }
        }
        __syncthreads();
#pragma unroll
        for (int i = 0; i < 8; ++i) {
            int id = tid + 256 * i;          // 0..2047
            int lr = id >> 4;                // 0..127
            int lc = (id & 15) * 8;          // 0..120
            int grow = bm + lr;
            if (grow < nrows) {
                uint4 val = *(const uint4*)(Cs + lr * CS_STRIDE + lc);
                *(uint4*)((unsigned short*)Cv + (size_t)grow * ncols + bn + lc) = val;
            }
        }
    } else {
        // EP == 3: per-thread chunk fold. Thread (wn,l16) owns feature
        // jf = bn/4 + wn*16 + l16; its 4 chunks are acc[mi][0..3][r].
        unsigned short* Cs2 = smem;
        int jfl = wn * 16 + l16;                   // 0..31 (tile-local feature)
        int jf  = (bn >> 2) + jfl;                 // 0..255 global feature col
        float bv0 = bias[jf];
        float bv1 = bias[256 + jf];
        float bv2 = bias[512 + jf];
        float bv3 = bias[768 + jf];
#pragma unroll
        for (int mi = 0; mi < 4; ++mi) {
#pragma unroll
            for (int r = 0; r < 4; ++r) {
                float v = gelu_f(acc[mi][0][r] + bv0) + gelu_f(acc[mi][1][r] + bv1)
                        + gelu_f(acc[mi][2][r] + bv2) + gelu_f(acc[mi][3][r] + bv3);
                int lr = wm * 64 + mi * 16 + quad * 4 + r;
                Cs2[lr * CS2_STRIDE + jfl] = f2b(v);
            }
        }
        __syncthreads();
#pragma unroll
        for (int i = 0; i < 2; ++i) {
            int id = tid + 256 * i;          // 0..511
            int lr = id >> 2;                // 0..127
            int q  = id & 3;                 // 4 x 8 shorts per row
            int grow = bm + lr;
            if (grow < nrows) {
                uint4 val = *(const uint4*)(Cs2 + lr * CS2_STRIDE + q * 8);
                *(uint4*)((unsigned short*)Cv + (size_t)grow * 256 + (bn >> 2) + q * 8) = val;
            }
        }
    }
}

// ---------------------------------------------------------------- fused GAT edge phase
// One node per 64-thread block + ring-8 (R8-proven config; ring-16 was null).

__global__ __launch_bounds__(64) void gat_fused(const unsigned short* __restrict__ zb,
                                                const float* __restrict__ att,
                                                const unsigned int* __restrict__ soff,
                                                const int* __restrict__ astart,
                                                const int* __restrict__ aend,
                                                const unsigned short* __restrict__ hnb,
                                                const float* __restrict__ g,
                                                const float* __restrict__ b,
                                                unsigned short* __restrict__ xrb, int nrows) {
    int lane = threadIdx.x;
    int n = blockIdx.x;
    int p0  = astart[n];
    int end = aend[n];

    ushort4 zlu = *(const ushort4*)(zb + (size_t)n * 512 + lane * 4);
    float zl0 = b2f(zlu.x), zl1 = b2f(zlu.y), zl2 = b2f(zlu.z), zl3 = b2f(zlu.w);
    float4 a4 = *(const float4*)(att + lane * 4);

    const char* zrb = (const char*)zb + 512;          // zr base (uniform)
    const unsigned int loff = (unsigned int)lane * 8u;

    float denom = 0.f;
    float ax = 0.f, ay = 0.f, az = 0.f, aw = 0.f;

    auto edge4 = [&](uint2 u0, uint2 u1, uint2 u2, uint2 u3, int pb) {
        float z00, z01, z02, z03, z10, z11, z12, z13;
        float z20, z21, z22, z23, z30, z31, z32, z33;
        b2f2(u0.x, z00, z01); b2f2(u0.y, z02, z03);
        b2f2(u1.x, z10, z11); b2f2(u1.y, z12, z13);
        b2f2(u2.x, z20, z21); b2f2(u2.y, z22, z23);
        b2f2(u3.x, z30, z31); b2f2(u3.y, z32, z33);

        float v00 = zl0 + z00, v01 = zl1 + z01, v02 = zl2 + z02, v03 = zl3 + z03;
        float v10 = zl0 + z10, v11 = zl1 + z11, v12 = zl2 + z12, v13 = zl3 + z13;
        float v20 = zl0 + z20, v21 = zl1 + z21, v22 = zl2 + z22, v23 = zl3 + z23;
        float v30 = zl0 + z30, v31 = zl1 + z31, v32 = zl2 + z32, v33 = zl3 + z33;
        v00 = fmaxf(v00, 0.2f * v00); v01 = fmaxf(v01, 0.2f * v01);
        v02 = fmaxf(v02, 0.2f * v02); v03 = fmaxf(v03, 0.2f * v03);
        v10 = fmaxf(v10, 0.2f * v10); v11 = fmaxf(v11, 0.2f * v11);
        v12 = fmaxf(v12, 0.2f * v12); v13 = fmaxf(v13, 0.2f * v13);
        v20 = fmaxf(v20, 0.2f * v20); v21 = fmaxf(v21, 0.2f * v21);
        v22 = fmaxf(v22, 0.2f * v22); v23 = fmaxf(v23, 0.2f * v23);
        v30 = fmaxf(v30, 0.2f * v30); v31 = fmaxf(v31, 0.2f * v31);
        v32 = fmaxf(v32, 0.2f * v32); v33 = fmaxf(v33, 0.2f * v33);
        float q0 = a4.x * v00 + a4.y * v01 + a4.z * v02 + a4.w * v03;
        float q1 = a4.x * v10 + a4.y * v11 + a4.z * v12 + a4.w * v13;
        float q2 = a4.x * v20 + a4.y * v21 + a4.z * v22 + a4.w * v23;
        float q3 = a4.x * v30 + a4.y * v31 + a4.z * v32 + a4.w * v33;
        float s0 = quad16_sum(q0);        // per-head (quad) score, DPP
        float s1 = quad16_sum(q1);
        float s2 = quad16_sum(q2);
        float s3 = quad16_sum(q3);
        float w0 = __expf(s0);
        float w1 = (pb + 1 < end) ? __expf(s1) : 0.0f;
        float w2 = (pb + 2 < end) ? __expf(s2) : 0.0f;
        float w3 = (pb + 3 < end) ? __expf(s3) : 0.0f;
        denom += (w0 + w1) + (w2 + w3);
        ax += (w0 * z00 + w1 * z10) + (w2 * z20 + w3 * z30);
        ay += (w0 * z01 + w1 * z11) + (w2 * z21 + w3 * z31);
        az += (w0 * z02 + w1 * z12) + (w2 * z22 + w3 * z32);
        aw += (w0 * z03 + w1 * z13) + (w2 * z23 + w3 * z33);
    };

    uint4 oA = *(const uint4*)(soff + p0);
    uint2 cA0 = *(const uint2*)(zrb + (oA.x + loff));
    uint2 cA1 = *(const uint2*)(zrb + (oA.y + loff));
    uint2 cA2 = *(const uint2*)(zrb + (oA.z + loff));
    uint2 cA3 = *(const uint2*)(zrb + (oA.w + loff));
    uint4 oB = *(const uint4*)(soff + p0 + 4);
    uint2 cB0 = *(const uint2*)(zrb + (oB.x + loff));
    uint2 cB1 = *(const uint2*)(zrb + (oB.y + loff));
    uint2 cB2 = *(const uint2*)(zrb + (oB.z + loff));
    uint2 cB3 = *(const uint2*)(zrb + (oB.w + loff));

    for (int p = p0; p < end; p += 8) {
        edge4(cA0, cA1, cA2, cA3, p);
        oA = *(const uint4*)(soff + p + 8);
        cA0 = *(const uint2*)(zrb + (oA.x + loff));
        cA1 = *(const uint2*)(zrb + (oA.y + loff));
        cA2 = *(const uint2*)(zrb + (oA.z + loff));
        cA3 = *(const uint2*)(zrb + (oA.w + loff));
        if (p + 4 >= end) break;     // wave-uniform
        edge4(cB0, cB1, cB2, cB3, p + 4);
        oB = *(const uint4*)(soff + p + 12);
        cB0 = *(const uint2*)(zrb + (oB.x + loff));
        cB1 = *(const uint2*)(zrb + (oB.y + loff));
        cB2 = *(const uint2*)(zrb + (oB.z + loff));
        cB3 = *(const uint2*)(zrb + (oB.w + loff));
    }

    size_t idx = (size_t)n * DHID + lane * 4;
    ushort4 ru = *(const ushort4*)(hnb + idx);
    float inv = 1.0f / (denom + 1e-9f);
    float4 o;
    o.x = ax * inv + b2f(ru.x);
    o.y = ay * inv + b2f(ru.y);
    o.z = az * inv + b2f(ru.z);
    o.w = aw * inv + b2f(ru.w);
    float sum = wave_sum(o.x + o.y + o.z + o.w);
    float sq  = wave_sum(o.x * o.x + o.y * o.y + o.z * o.z + o.w * o.w);
    float mean = sum * (1.0f / DHID);
    float var  = sq * (1.0f / DHID) - mean * mean;
    float rnorm = rsqrtf(fmaxf(var, 0.0f) + 1e-3f);
    float4 gv = *(const float4*)(g + lane * 4);
    float4 bv = *(const float4*)(b + lane * 4);
    float4 y;
    y.x = (o.x - mean) * rnorm * gv.x + bv.x;
    y.y = (o.y - mean) * rnorm * gv.y + bv.y;
    y.z = (o.z - mean) * rnorm * gv.z + bv.z;
    y.w = (o.w - mean) * rnorm * gv.w + bv.w;
    ushort4 ob;
    ob.x = f2b(y.x); ob.y = f2b(y.y); ob.z = f2b(y.z); ob.w = f2b(y.w);
    *(ushort4*)(xrb + idx) = ob;
}

// ---------------------------------------------------------------- host

extern "C" void kernel_launch(void* const* d_in, const int* in_sizes, int n_in,
                              void* d_out, int out_size, void* d_ws, size_t ws_size,
                              hipStream_t stream) {
    const float* x       = (const float*)d_in[0];
    const float* head_W  = (const float*)d_in[1];
    const float* head_b  = (const float*)d_in[2];
    const float* ng_g    = (const float*)d_in[3];
    const float* ng_b    = (const float*)d_in[4];
    const float* Wl      = (const float*)d_in[5];
    const float* Wr      = (const float*)d_in[6];
    const float* att     = (const float*)d_in[7];
    const float* nd_g    = (const float*)d_in[8];
    const float* nd_b    = (const float*)d_in[9];
    const float* dense_W = (const float*)d_in[10];
    const float* dense_b = (const float*)d_in[11];
    const float* tail_W  = (const float*)d_in[12];
    const float* tail_b  = (const float*)d_in[13];
    const int*   edges   = (const int*)d_in[14];
    float* out = (float*)d_out;

    const size_t NH = (size_t)NN * DHID;  // 5,120,000
    const int SOFF_LEN = EE + 4 * NN + 16;  // padded offset buffer length
    // ---- workspace layout (liveness-checked; zb/d union is deliberate) ----
    float* xr = (float*)d_ws;                           // NH f32 (head output only)
    float* hn = xr + NH;                                // NH f32, repurposed as int pool
    unsigned short* hnb = (unsigned short*)(hn + NH);   // NH bf16
    unsigned short* xrb = hnb + NH;                     // NH bf16
    unsigned short* U   = xrb + NH;                     // union region, 4*NH shorts
    unsigned short* zb  = U;                            //   N x 512 bf16  (dies at gat_fused)
    unsigned short* d_buf = U;                          //   N x 256 bf16 (written after gat_fused)
    unsigned short* headT  = U + 4 * NH;
    unsigned short* WzT    = headT + 65536;             // 4 x (512 x 256)
    unsigned short* denseT = WzT + 524288;              // 4 x (1024 x 256, permuted rows)
    unsigned short* tailT  = denseT + 1048576;          // 64 x 256
    int* counts  = (int*)(tailT + 16384);
    int* bsums   = counts + NN;
    int* excl    = bsums + 32;
    int* cursor  = excl + NN;
    // int pool inside dead hn region (20 MB):
    unsigned int* soff = (unsigned int*)hn;             // SOFF_LEN
    int* astart = (int*)(soff + SOFF_LEN);              // NN
    int* aendp  = astart + NN;                          // NN

    // CSR build (4-aligned, zero-padded, byte offsets)
    hipMemsetAsync(counts, 0, NN * sizeof(int), stream);
    hipMemsetAsync(soff, 0, SOFF_LEN * sizeof(int), stream);
    hist_kernel<<<(EE + 255) / 256, 256, 0, stream>>>(edges, counts, EE);
    scan_block<<<(NN + 1023) / 1024, 1024, 0, stream>>>(counts, excl, bsums, NN);
    scan_fix2<<<(NN + 255) / 256, 256, 0, stream>>>(excl, bsums, counts, astart, aendp, cursor, NN);
    scatter2<<<(EE + 255) / 256, 256, 0, stream>>>(edges, cursor, soff, EE);

    // weight prep
    transpose_bf16<<<dim3(8, 8, 1), 256, 0, stream>>>(head_W, headT, 256, 256, 0, 0);
    transpose_bf16<<<dim3(8, 8, 4), 256, 0, stream>>>(Wl, WzT, 256, 256, 65536, 131072);
    transpose_bf16<<<dim3(8, 8, 4), 256, 0, stream>>>(Wr, WzT + 65536, 256, 256, 65536, 131072);
    transpose_perm<<<dim3(32, 8, 4), 256, 0, stream>>>(dense_W, denseT, 256, 1024, 262144, 262144);
    transpose_bf16<<<dim3(2, 8, 1), 256, 0, stream>>>(tail_W, tailT, 256, 64, 0, 0);
    convert_bf16<<<(int)(NH / 4 + 255) / 256, 256, 0, stream>>>(x, hnb, (int)(NH / 4));

    const int GXP = 160;  // multiple of 8 -> XCD = bx & 7 for every by
    // head: xr = x @ head_W + head_b (fp32)
    gemm128<0><<<dim3(GXP, 2), 256, 0, stream>>>(hnb, headT, head_b, xr, NN, 256);

    for (int l = 0; l < 4; ++l) {
        if (l == 0)
            ln_kernel<<<NN / 4, 256, 0, stream>>>(xr, ng_g, ng_b, hnb, NN);
        else
            ln_dense<<<NN / 4, 256, 0, stream>>>(d_buf, xrb, ng_g + l * 256, ng_b + l * 256, hnb, NN);
        // [zl|zr] = hn @ [Wl|Wr]
        gemm128<1><<<dim3(GXP, 4), 256, 0, stream>>>(hnb, WzT + (size_t)l * 131072, nullptr, zb, NN, 512);
        // fused scores + plain-exp softmax agg + residual + LayerNorm (bf16 residual)
        gat_fused<<<NN, 64, 0, stream>>>(zb, att + l * 256, soff, astart, aendp, hnb,
                                         nd_g + l * 256, nd_b + l * 256, xrb, NN);
        // d = sum_c gelu(xr @ dense_W + dense_b) folded in-GEMM (N x 256 bf16) — clobbers zb (dead)
        gemm128<3><<<dim3(GXP, 8), 256, 0, stream>>>(xrb, denseT + (size_t)l * 262144,
                                                     dense_b + l * 1024, d_buf, NN, 1024);
    }
    // hb = bf16(d + xrb) -> hnb (dead); out = hb @ tail_W + tail_b
    combine_final<<<NN / 4, 256, 0, stream>>>(d_buf, xrb, hnb, NN);
    gemm128<0><<<dim3(GXP, 1), 256, 0, stream>>>(hnb, tailT, tail_b, out, NN, 64);
}

// Round 11
// 527.724 us; speedup vs baseline: 1.0248x; 1.0248x over previous
//
#include <hip/hip_runtime.h>
#include <cstdint>

#define NN 20000
#define EE 320000
#define DHID 256

typedef short bf16x8 __attribute__((ext_vector_type(8)));
typedef float f32x4 __attribute__((ext_vector_type(4)));

// ---------------------------------------------------------------- utilities

__device__ __forceinline__ float b2f(unsigned short u) {
    union { unsigned int i; float f; } v;
    v.i = ((unsigned int)u) << 16;
    return v.f;
}

__device__ __forceinline__ void b2f2(unsigned int w, float& lo, float& hi) {
    union { unsigned int i; float f; } a, c;
    a.i = w << 16;
    c.i = w & 0xffff0000u;
    lo = a.f;
    hi = c.f;
}

__device__ __forceinline__ unsigned short f2b(float x) {
    union { float f; unsigned int i; } v;
    v.f = x;
    unsigned int r = (v.i + 0x7FFFu + ((v.i >> 16) & 1u)) >> 16;
    return (unsigned short)r;
}

__device__ __forceinline__ float wave_sum(float v) {
#pragma unroll
    for (int m = 1; m < 64; m <<= 1) v += __shfl_xor(v, m);
    return v;
}

// 16-lane full sum via DPP row rotations (pure VALU, no LDS/bpermute ops).
#define DPP_ROR_ADD(v, n)                                                                  \
    v += __int_as_float(__builtin_amdgcn_update_dpp(__float_as_int(v), __float_as_int(v),  \
                                                    0x120 + (n), 0xF, 0xF, 0))
__device__ __forceinline__ float quad16_sum(float v) {
    DPP_ROR_ADD(v, 8);
    DPP_ROR_ADD(v, 4);
    DPP_ROR_ADD(v, 2);
    DPP_ROR_ADD(v, 1);
    return v;
}

// gelu tanh-approx, algebra-reduced: gelu = x*(1 - 1/(e+1)), e = exp(2z).
__device__ __forceinline__ float gelu_f(float x) {
    float x2 = x * x;
    float p  = fmaf(0.044715f, x2, 1.0f);
    float e  = __expf(x * p * 1.5957691216f);   // exp(2z)
    float r  = 1.0f / (e + 1.0f);
    return x - x * r;
}

// async global->LDS, 16B per lane; lds dest is wave-uniform base (+HW lane*16)
__device__ __forceinline__ void gld16(const unsigned short* g, unsigned short* lds) {
    __builtin_amdgcn_global_load_lds((const __attribute__((address_space(1))) unsigned int*)g,
                                     (__attribute__((address_space(3))) unsigned int*)lds, 16, 0, 0);
}

// ---------------------------------------------------------------- CSR build (4-aligned, padded, byte offsets)

__global__ void hist_kernel(const int* __restrict__ edges, int* __restrict__ counts, int E_) {
    int e = blockIdx.x * 256 + threadIdx.x;
    if (e >= E_) return;
    atomicAdd(&counts[edges[e * 2]], 1);
}

// scan over PADDED counts ((c+3)&~3), padding folded in here
__global__ __launch_bounds__(1024) void scan_block(const int* __restrict__ counts,
                                                   int* __restrict__ excl,
                                                   int* __restrict__ bsums, int n) {
    __shared__ int sd[1024];
    int tid = threadIdx.x;
    int i = blockIdx.x * 1024 + tid;
    int c = (i < n) ? ((counts[i] + 3) & ~3) : 0;
    sd[tid] = c;
    __syncthreads();
#pragma unroll
    for (int off = 1; off < 1024; off <<= 1) {
        int v = (tid >= off) ? sd[tid - off] : 0;
        __syncthreads();
        sd[tid] += v;
        __syncthreads();
    }
    if (i < n) excl[i] = sd[tid] - c;
    if (tid == 1023) bsums[blockIdx.x] = sd[1023];
}

// astart (aligned start), aend = astart + true degree, cursor = astart.
// bsums holds RAW per-block sums; prefix over <=20 entries computed inline.
__global__ void scan_fix2(const int* __restrict__ excl, const int* __restrict__ bsums,
                          const int* __restrict__ counts,
                          int* __restrict__ astart, int* __restrict__ aend,
                          int* __restrict__ cursor, int n) {
    int i = blockIdx.x * 256 + threadIdx.x;
    if (i < n) {
        int blk = i >> 10;
        int base = 0;
        for (int j = 0; j < blk; ++j) base += bsums[j];
        int v = excl[i] + base;
        astart[i] = v;
        cursor[i] = v;
        aend[i]   = v + counts[i];
    }
}

__global__ void scatter2(const int* __restrict__ edges, int* __restrict__ cursor,
                         unsigned int* __restrict__ soff, int E_) {
    int e = blockIdx.x * 256 + threadIdx.x;
    if (e >= E_) return;
    int dstn = edges[e * 2];
    int src  = edges[e * 2 + 1];
    int pos = atomicAdd(&cursor[dstn], 1);
    soff[pos] = (unsigned int)src << 10;   // byte offset into zr (512 shorts/row)
}

// ---------------------------------------------------------------- weight transpose: W (K x M) fp32 -> Wt (M x K) bf16

__global__ __launch_bounds__(256) void transpose_bf16(const float* __restrict__ W,
                                                      unsigned short* __restrict__ Wt,
                                                      int K, int M, size_t lsW, size_t lsT) {
    W  += (size_t)blockIdx.z * lsW;
    Wt += (size_t)blockIdx.z * lsT;
    __shared__ float sm[32][33];
    int m0 = blockIdx.x * 32, k0 = blockIdx.y * 32;
    int tx = threadIdx.x & 31, ty = threadIdx.x >> 5;
#pragma unroll
    for (int i = 0; i < 4; ++i)
        sm[ty + i * 8][tx] = W[(size_t)(k0 + ty + i * 8) * M + m0 + tx];
    __syncthreads();
#pragma unroll
    for (int i = 0; i < 4; ++i)
        Wt[(size_t)(m0 + ty + i * 8) * K + k0 + tx] = f2b(sm[tx][ty + i * 8]);
}

// dense_W variant: column m = c*256 + j (c = chunk, j = feature) mapped to row
// cc = (by<<7)|((t>>4)<<6)|(c<<4)|(t&15) with by = j>>5, t = j&31, so that in the
// 128x128 GEMM tile a feature's 4 chunks land in ONE thread's 4 ni accumulators.
__global__ __launch_bounds__(256) void transpose_perm(const float* __restrict__ W,
                                                      unsigned short* __restrict__ Wt,
                                                      int K, int M, size_t lsW, size_t lsT) {
    W  += (size_t)blockIdx.z * lsW;
    Wt += (size_t)blockIdx.z * lsT;
    __shared__ float sm[32][33];
    int m0 = blockIdx.x * 32, k0 = blockIdx.y * 32;
    int tx = threadIdx.x & 31, ty = threadIdx.x >> 5;
#pragma unroll
    for (int i = 0; i < 4; ++i)
        sm[ty + i * 8][tx] = W[(size_t)(k0 + ty + i * 8) * M + m0 + tx];
    __syncthreads();
#pragma unroll
    for (int i = 0; i < 4; ++i) {
        int mm = m0 + ty + i * 8;
        int c = mm >> 8, j = mm & 255;
        int by = j >> 5, t = j & 31;
        int cc = (by << 7) | ((t >> 4) << 6) | (c << 4) | (t & 15);
        Wt[(size_t)cc * K + k0 + tx] = f2b(sm[tx][ty + i * 8]);
    }
}

__global__ void convert_bf16(const float* __restrict__ in, unsigned short* __restrict__ out, int n4) {
    int i = blockIdx.x * 256 + threadIdx.x;
    if (i >= n4) return;
    float4 v = *(const float4*)(in + (size_t)i * 4);
    ushort4 o;
    o.x = f2b(v.x); o.y = f2b(v.y); o.z = f2b(v.z); o.w = f2b(v.w);
    *(ushort4*)(out + (size_t)i * 4) = o;
}

// ---------------------------------------------------------------- LayerNorm (fp32 in -> bf16 out only)

__global__ __launch_bounds__(256) void ln_kernel(const float* __restrict__ X,
                                                 const float* __restrict__ g,
                                                 const float* __restrict__ b,
                                                 unsigned short* __restrict__ Yb, int nrows) {
    int row = blockIdx.x * 4 + (threadIdx.x >> 6);
    int lane = threadIdx.x & 63;
    if (row >= nrows) return;
    float4 v = *(const float4*)(X + (size_t)row * DHID + lane * 4);
    float sum = wave_sum(v.x + v.y + v.z + v.w);
    float sq  = wave_sum(v.x * v.x + v.y * v.y + v.z * v.z + v.w * v.w);
    float mean = sum * (1.0f / DHID);
    float var  = sq * (1.0f / DHID) - mean * mean;
    float r = rsqrtf(fmaxf(var, 0.0f) + 1e-3f);
    float4 gv = *(const float4*)(g + lane * 4);
    float4 bv = *(const float4*)(b + lane * 4);
    float4 o;
    o.x = (v.x - mean) * r * gv.x + bv.x;
    o.y = (v.y - mean) * r * gv.y + bv.y;
    o.z = (v.z - mean) * r * gv.z + bv.z;
    o.w = (v.w - mean) * r * gv.w + bv.w;
    ushort4 ob;
    ob.x = f2b(o.x); ob.y = f2b(o.y); ob.z = f2b(o.z); ob.w = f2b(o.w);
    *(ushort4*)(Yb + (size_t)row * DHID + lane * 4) = ob;
}

// LayerNorm over (dense-sum d + residual xrb), both bf16 N x 256
__global__ __launch_bounds__(256) void ln_dense(const unsigned short* __restrict__ d,
                                                const unsigned short* __restrict__ xrb,
                                                const float* __restrict__ g,
                                                const float* __restrict__ b,
                                                unsigned short* __restrict__ Yb, int nrows) {
    int row = blockIdx.x * 4 + (threadIdx.x >> 6);
    int lane = threadIdx.x & 63;
    if (row >= nrows) return;
    ushort4 xu = *(const ushort4*)(xrb + (size_t)row * DHID + lane * 4);
    ushort4 du = *(const ushort4*)(d   + (size_t)row * DHID + lane * 4);
    float4 v;
    v.x = b2f(xu.x) + b2f(du.x);
    v.y = b2f(xu.y) + b2f(du.y);
    v.z = b2f(xu.z) + b2f(du.z);
    v.w = b2f(xu.w) + b2f(du.w);
    float sum = wave_sum(v.x + v.y + v.z + v.w);
    float sq  = wave_sum(v.x * v.x + v.y * v.y + v.z * v.z + v.w * v.w);
    float mean = sum * (1.0f / DHID);
    float var  = sq * (1.0f / DHID) - mean * mean;
    float r = rsqrtf(fmaxf(var, 0.0f) + 1e-3f);
    float4 gv = *(const float4*)(g + lane * 4);
    float4 bv = *(const float4*)(b + lane * 4);
    float4 o;
    o.x = (v.x - mean) * r * gv.x + bv.x;
    o.y = (v.y - mean) * r * gv.y + bv.y;
    o.z = (v.z - mean) * r * gv.z + bv.z;
    o.w = (v.w - mean) * r * gv.w + bv.w;
    ushort4 ob;
    ob.x = f2b(o.x); ob.y = f2b(o.y); ob.z = f2b(o.z); ob.w = f2b(o.w);
    *(ushort4*)(Yb + (size_t)row * DHID + lane * 4) = ob;
}

// final combine (no LN): hb = bf16(d + xrb)
__global__ __launch_bounds__(256) void combine_final(const unsigned short* __restrict__ d,
                                                     const unsigned short* __restrict__ xrb,
                                                     unsigned short* __restrict__ hb, int nrows) {
    int row = blockIdx.x * 4 + (threadIdx.x >> 6);
    int lane = threadIdx.x & 63;
    if (row >= nrows) return;
    ushort4 xu = *(const ushort4*)(xrb + (size_t)row * DHID + lane * 4);
    ushort4 du = *(const ushort4*)(d   + (size_t)row * DHID + lane * 4);
    ushort4 ob;
    ob.x = f2b(b2f(xu.x) + b2f(du.x));
    ob.y = f2b(b2f(xu.y) + b2f(du.y));
    ob.z = f2b(b2f(xu.z) + b2f(du.z));
    ob.w = f2b(b2f(xu.w) + b2f(du.w));
    *(ushort4*)(hb + (size_t)row * DHID + lane * 4) = ob;
}

// ---------------------------------------------------------------- MFMA GEMM, 128x128 tile, BK=64
// A: nrows x 256 bf16 (k contig); B: ncols x 256 bf16 (k contig, i.e. W^T)
// EP: 0 = fp32 out (+bias), 1 = bf16 out,
//     3 = chunk-folded dense (B rows permuted so a feature's 4 chunks sit in one
//         thread's 4 ni accs): out[row][jf] = sum_ni gelu(acc[mi][ni][r]+bias) — no shuffles
// Grid-x padded to multiple of 8 -> XCD = bx & 7 for all by (A fetched once).
// (256,3): R8-proven; (256,4) was null-to-negative in R10.

#define CS_STRIDE 140   // 128 + 12 shorts (EP1 staging)
#define CS2_STRIDE 40   // 32 + 8 shorts (EP3 staging; 80B rows keep 16B alignment)

template <int EP>
__global__ __launch_bounds__(256, 3) void gemm128(const unsigned short* __restrict__ A,
                                                  const unsigned short* __restrict__ B,
                                                  const float* __restrict__ bias,
                                                  void* __restrict__ Cv, int nrows, int ncols) {
    __shared__ unsigned short smem[128 * CS_STRIDE];  // 35840 B; >= As(16KB)+Bs(16KB)
    unsigned short* As = smem;                        // 8192 shorts (128 rows x 64 k)
    unsigned short* Bs = smem + 8192;                 // 8192 shorts (128 cols x 64 k)
    unsigned short* Cs = smem;                        // epilogue alias (after final barrier)
    const int bm = blockIdx.x * 128, bn = blockIdx.y * 128;
    if (bm >= nrows) return;  // grid-x padding
    const int tid  = threadIdx.x;
    const int w    = tid >> 6, lane = tid & 63;
    const int quad = lane >> 4, l16 = lane & 15;
    const int wm = w >> 1, wn = w & 1;

    const int srow = lane & 15;
    const int sg   = lane >> 4;   // 0..3
    int ga0 = min(bm + w * 32 + srow,      nrows - 1);
    int ga1 = min(bm + w * 32 + 16 + srow, nrows - 1);
    int gb0 = min(bn + w * 32 + srow,      ncols - 1);
    int gb1 = min(bn + w * 32 + 16 + srow, ncols - 1);
    const unsigned short* Ap0 = A + (size_t)ga0 * 256 + sg * 8;
    const unsigned short* Ap1 = A + (size_t)ga1 * 256 + sg * 8;
    const unsigned short* Bp0 = B + (size_t)gb0 * 256 + sg * 8;
    const unsigned short* Bp1 = B + (size_t)gb1 * 256 + sg * 8;
    unsigned short* la0 = As + (2 * w) * 1024;
    unsigned short* la1 = As + (2 * w + 1) * 1024;
    unsigned short* lb0 = Bs + (2 * w) * 1024;
    unsigned short* lb1 = Bs + (2 * w + 1) * 1024;

    f32x4 acc[4][4] = {};
    for (int k0 = 0; k0 < 256; k0 += 64) {
        gld16(Ap0 + k0,      la0);
        gld16(Ap0 + k0 + 32, la0 + 512);
        gld16(Ap1 + k0,      la1);
        gld16(Ap1 + k0 + 32, la1 + 512);
        gld16(Bp0 + k0,      lb0);
        gld16(Bp0 + k0 + 32, lb0 + 512);
        gld16(Bp1 + k0,      lb1);
        gld16(Bp1 + k0 + 32, lb1 + 512);
        __syncthreads();
#pragma unroll
        for (int kk = 0; kk < 2; ++kk) {
            bf16x8 a[4], b[4];
#pragma unroll
            for (int mi = 0; mi < 4; ++mi)
                a[mi] = *(const bf16x8*)(As + (wm * 4 + mi) * 1024 + (kk * 4 + quad) * 128 + l16 * 8);
#pragma unroll
            for (int ni = 0; ni < 4; ++ni)
                b[ni] = *(const bf16x8*)(Bs + (wn * 4 + ni) * 1024 + (kk * 4 + quad) * 128 + l16 * 8);
#pragma unroll
            for (int mi = 0; mi < 4; ++mi)
#pragma unroll
                for (int ni = 0; ni < 4; ++ni)
                    acc[mi][ni] = __builtin_amdgcn_mfma_f32_16x16x32_bf16(a[mi], b[ni], acc[mi][ni], 0, 0, 0);
        }
        __syncthreads();
    }

    if (EP == 0) {
        // fp32 out (head/tail): direct stores
#pragma unroll
        for (int ni = 0; ni < 4; ++ni) {
            int col = bn + wn * 64 + ni * 16 + l16;
            if (col >= ncols) continue;
            float bv = bias ? bias[col] : 0.0f;
#pragma unroll
            for (int mi = 0; mi < 4; ++mi) {
#pragma unroll
                for (int r = 0; r < 4; ++r) {
                    int row = bm + wm * 64 + mi * 16 + quad * 4 + r;
                    if (row < nrows) ((float*)Cv)[(size_t)row * ncols + col] = acc[mi][ni][r] + bv;
                }
            }
        }
    } else if (EP == 1) {
        // bf16 out: stage tile in Cs, coalesced 16B stores
#pragma unroll
        for (int ni = 0; ni < 4; ++ni) {
            int lc = wn * 64 + ni * 16 + l16;
#pragma unroll
            for (int mi = 0; mi < 4; ++mi) {
#pragma unroll
                for (int r = 0; r < 4; ++r) {
                    int lr = wm * 64 + mi * 16 + quad * 4 + r;
                    Cs[lr * CS_STRIDE + lc] = f2b(acc[mi][ni][r]);
                }
            }
        }
        __syncthreads();
#pragma unroll
        for (int i = 0; i < 8; ++i) {
            int id = tid + 256 * i;          // 0..2047
            int lr = id >> 4;                // 0..127
            int lc = (id & 15) * 8;          // 0..120
            int grow = bm + lr;
            if (grow < nrows) {
                uint4 val = *(const uint4*)(Cs + lr * CS_STRIDE + lc);
                *(uint4*)((unsigned short*)Cv + (size_t)grow * ncols + bn + lc) = val;
            }
        }
    } else {
        // EP == 3: per-thread chunk fold. Thread (wn,l16) owns feature
        // jf = bn/4 + wn*16 + l16; its 4 chunks are acc[mi][0..3][r].
        unsigned short* Cs2 = smem;
        int jfl = wn * 16 + l16;                   // 0..31 (tile-local feature)
        int jf  = (bn >> 2) + jfl;                 // 0..255 global feature col
        float bv0 = bias[jf];
        float bv1 = bias[256 + jf];
        float bv2 = bias[512 + jf];
        float bv3 = bias[768 + jf];
#pragma unroll
        for (int mi = 0; mi < 4; ++mi) {
#pragma unroll
            for (int r = 0; r < 4; ++r) {
                float v = gelu_f(acc[mi][0][r] + bv0) + gelu_f(acc[mi][1][r] + bv1)
                        + gelu_f(acc[mi][2][r] + bv2) + gelu_f(acc[mi][3][r] + bv3);
                int lr = wm * 64 + mi * 16 + quad * 4 + r;
                Cs2[lr * CS2_STRIDE + jfl] = f2b(v);
            }
        }
        __syncthreads();
#pragma unroll
        for (int i = 0; i < 2; ++i) {
            int id = tid + 256 * i;          // 0..511
            int lr = id >> 2;                // 0..127
            int q  = id & 3;                 // 4 x 8 shorts per row
            int grow = bm + lr;
            if (grow < nrows) {
                uint4 val = *(const uint4*)(Cs2 + lr * CS2_STRIDE + q * 8);
                *(uint4*)((unsigned short*)Cv + (size_t)grow * 256 + (bn >> 2) + q * 8) = val;
            }
        }
    }
}

// ---------------------------------------------------------------- fused GAT edge phase
// R11: TWO waves per node (128-thread block). Wave w processes interleaved 4-edge
// groups (stride 8 edges), each with its own ring-2x4 prefetch (distance 16 of its
// stream — same per-wave depth as R8). Partial sums combined via LDS; wave 0 does
// the LN epilogue. Halves the per-wave serial edge chain.

__global__ __launch_bounds__(128) void gat_fused(const unsigned short* __restrict__ zb,
                                                 const float* __restrict__ att,
                                                 const unsigned int* __restrict__ soff,
                                                 const int* __restrict__ astart,
                                                 const int* __restrict__ aend,
                                                 const unsigned short* __restrict__ hnb,
                                                 const float* __restrict__ g,
                                                 const float* __restrict__ b,
                                                 unsigned short* __restrict__ xrb, int nrows) {
    __shared__ float red[5][64];
    int lane = threadIdx.x & 63;
    int wv   = threadIdx.x >> 6;          // 0 or 1
    int n = blockIdx.x;
    int p0  = astart[n];
    int end = aend[n];

    ushort4 zlu = *(const ushort4*)(zb + (size_t)n * 512 + lane * 4);
    float zl0 = b2f(zlu.x), zl1 = b2f(zlu.y), zl2 = b2f(zlu.z), zl3 = b2f(zlu.w);
    float4 a4 = *(const float4*)(att + lane * 4);

    const char* zrb = (const char*)zb + 512;          // zr base (uniform)
    const unsigned int loff = (unsigned int)lane * 8u;

    float denom = 0.f;
    float ax = 0.f, ay = 0.f, az = 0.f, aw = 0.f;

    auto edge4 = [&](uint2 u0, uint2 u1, uint2 u2, uint2 u3, int pb) {
        float z00, z01, z02, z03, z10, z11, z12, z13;
        float z20, z21, z22, z23, z30, z31, z32, z33;
        b2f2(u0.x, z00, z01); b2f2(u0.y, z02, z03);
        b2f2(u1.x, z10, z11); b2f2(u1.y, z12, z13);
        b2f2(u2.x, z20, z21); b2f2(u2.y, z22, z23);
        b2f2(u3.x, z30, z31); b2f2(u3.y, z32, z33);

        float v00 = zl0 + z00, v01 = zl1 + z01, v02 = zl2 + z02, v03 = zl3 + z03;
        float v10 = zl0 + z10, v11 = zl1 + z11, v12 = zl2 + z12, v13 = zl3 + z13;
        float v20 = zl0 + z20, v21 = zl1 + z21, v22 = zl2 + z22, v23 = zl3 + z23;
        float v30 = zl0 + z30, v31 = zl1 + z31, v32 = zl2 + z32, v33 = zl3 + z33;
        v00 = fmaxf(v00, 0.2f * v00); v01 = fmaxf(v01, 0.2f * v01);
        v02 = fmaxf(v02, 0.2f * v02); v03 = fmaxf(v03, 0.2f * v03);
        v10 = fmaxf(v10, 0.2f * v10); v11 = fmaxf(v11, 0.2f * v11);
        v12 = fmaxf(v12, 0.2f * v12); v13 = fmaxf(v13, 0.2f * v13);
        v20 = fmaxf(v20, 0.2f * v20); v21 = fmaxf(v21, 0.2f * v21);
        v22 = fmaxf(v22, 0.2f * v22); v23 = fmaxf(v23, 0.2f * v23);
        v30 = fmaxf(v30, 0.2f * v30); v31 = fmaxf(v31, 0.2f * v31);
        v32 = fmaxf(v32, 0.2f * v32); v33 = fmaxf(v33, 0.2f * v33);
        float q0 = a4.x * v00 + a4.y * v01 + a4.z * v02 + a4.w * v03;
        float q1 = a4.x * v10 + a4.y * v11 + a4.z * v12 + a4.w * v13;
        float q2 = a4.x * v20 + a4.y * v21 + a4.z * v22 + a4.w * v23;
        float q3 = a4.x * v30 + a4.y * v31 + a4.z * v32 + a4.w * v33;
        float s0 = quad16_sum(q0);        // per-head (quad) score, DPP
        float s1 = quad16_sum(q1);
        float s2 = quad16_sum(q2);
        float s3 = quad16_sum(q3);
        float w0 = __expf(s0);
        float w1 = (pb + 1 < end) ? __expf(s1) : 0.0f;
        float w2 = (pb + 2 < end) ? __expf(s2) : 0.0f;
        float w3 = (pb + 3 < end) ? __expf(s3) : 0.0f;
        denom += (w0 + w1) + (w2 + w3);
        ax += (w0 * z00 + w1 * z10) + (w2 * z20 + w3 * z30);
        ay += (w0 * z01 + w1 * z11) + (w2 * z21 + w3 * z31);
        az += (w0 * z02 + w1 * z12) + (w2 * z22 + w3 * z32);
        aw += (w0 * z03 + w1 * z13) + (w2 * z23 + w3 * z33);
    };

    // wave wv owns groups at p0 + wv*4, stride 8; ring of 2 bodies (A at p, B at p+8),
    // prefetch distance 16 edges of own stream.
    int ps = p0 + wv * 4;
    uint4 oA = *(const uint4*)(soff + ps);
    uint2 cA0 = *(const uint2*)(zrb + (oA.x + loff));
    uint2 cA1 = *(const uint2*)(zrb + (oA.y + loff));
    uint2 cA2 = *(const uint2*)(zrb + (oA.z + loff));
    uint2 cA3 = *(const uint2*)(zrb + (oA.w + loff));
    uint4 oB = *(const uint4*)(soff + ps + 8);
    uint2 cB0 = *(const uint2*)(zrb + (oB.x + loff));
    uint2 cB1 = *(const uint2*)(zrb + (oB.y + loff));
    uint2 cB2 = *(const uint2*)(zrb + (oB.z + loff));
    uint2 cB3 = *(const uint2*)(zrb + (oB.w + loff));

    for (int p = ps; p < end; p += 16) {
        edge4(cA0, cA1, cA2, cA3, p);
        oA = *(const uint4*)(soff + p + 16);
        cA0 = *(const uint2*)(zrb + (oA.x + loff));
        cA1 = *(const uint2*)(zrb + (oA.y + loff));
        cA2 = *(const uint2*)(zrb + (oA.z + loff));
        cA3 = *(const uint2*)(zrb + (oA.w + loff));
        if (p + 8 >= end) break;     // wave-uniform
        edge4(cB0, cB1, cB2, cB3, p + 8);
        oB = *(const uint4*)(soff + p + 24);
        cB0 = *(const uint2*)(zrb + (oB.x + loff));
        cB1 = *(const uint2*)(zrb + (oB.y + loff));
        cB2 = *(const uint2*)(zrb + (oB.z + loff));
        cB3 = *(const uint2*)(zrb + (oB.w + loff));
    }

    // combine wave 1's partials into wave 0
    if (wv == 1) {
        red[0][lane] = denom;
        red[1][lane] = ax;
        red[2][lane] = ay;
        red[3][lane] = az;
        red[4][lane] = aw;
    }
    __syncthreads();
    if (wv == 1) return;
    denom += red[0][lane];
    ax += red[1][lane];
    ay += red[2][lane];
    az += red[3][lane];
    aw += red[4][lane];

    size_t idx = (size_t)n * DHID + lane * 4;
    ushort4 ru = *(const ushort4*)(hnb + idx);
    float inv = 1.0f / (denom + 1e-9f);
    float4 o;
    o.x = ax * inv + b2f(ru.x);
    o.y = ay * inv + b2f(ru.y);
    o.z = az * inv + b2f(ru.z);
    o.w = aw * inv + b2f(ru.w);
    float sum = wave_sum(o.x + o.y + o.z + o.w);
    float sq  = wave_sum(o.x * o.x + o.y * o.y + o.z * o.z + o.w * o.w);
    float mean = sum * (1.0f / DHID);
    float var  = sq * (1.0f / DHID) - mean * mean;
    float rnorm = rsqrtf(fmaxf(var, 0.0f) + 1e-3f);
    float4 gv = *(const float4*)(g + lane * 4);
    float4 bv = *(const float4*)(b + lane * 4);
    float4 y;
    y.x = (o.x - mean) * rnorm * gv.x + bv.x;
    y.y = (o.y - mean) * rnorm * gv.y + bv.y;
    y.z = (o.z - mean) * rnorm * gv.z + bv.z;
    y.w = (o.w - mean) * rnorm * gv.w + bv.w;
    ushort4 ob;
    ob.x = f2b(y.x); ob.y = f2b(y.y); ob.z = f2b(y.z); ob.w = f2b(y.w);
    *(ushort4*)(xrb + idx) = ob;
}

// ---------------------------------------------------------------- host

extern "C" void kernel_launch(void* const* d_in, const int* in_sizes, int n_in,
                              void* d_out, int out_size, void* d_ws, size_t ws_size,
                              hipStream_t stream) {
    const float* x       = (const float*)d_in[0];
    const float* head_W  = (const float*)d_in[1];
    const float* head_b  = (const float*)d_in[2];
    const float* ng_g    = (const float*)d_in[3];
    const float* ng_b    = (const float*)d_in[4];
    const float* Wl      = (const float*)d_in[5];
    const float* Wr      = (const float*)d_in[6];
    const float* att     = (const float*)d_in[7];
    const float* nd_g    = (const float*)d_in[8];
    const float* nd_b    = (const float*)d_in[9];
    const float* dense_W = (const float*)d_in[10];
    const float* dense_b = (const float*)d_in[11];
    const float* tail_W  = (const float*)d_in[12];
    const float* tail_b  = (const float*)d_in[13];
    const int*   edges   = (const int*)d_in[14];
    float* out = (float*)d_out;

    const size_t NH = (size_t)NN * DHID;  // 5,120,000
    const int SOFF_LEN = EE + 4 * NN + 32;  // padded offset buffer (2-wave ring lookahead)
    // ---- workspace layout (liveness-checked; zb/d union is deliberate) ----
    float* xr = (float*)d_ws;                           // NH f32 (head output only)
    float* hn = xr + NH;                                // NH f32, repurposed as int pool
    unsigned short* hnb = (unsigned short*)(hn + NH);   // NH bf16
    unsigned short* xrb = hnb + NH;                     // NH bf16
    unsigned short* U   = xrb + NH;                     // union region, 4*NH shorts
    unsigned short* zb  = U;                            //   N x 512 bf16  (dies at gat_fused)
    unsigned short* d_buf = U;                          //   N x 256 bf16 (written after gat_fused)
    unsigned short* headT  = U + 4 * NH;
    unsigned short* WzT    = headT + 65536;             // 4 x (512 x 256)
    unsigned short* denseT = WzT + 524288;              // 4 x (1024 x 256, permuted rows)
    unsigned short* tailT  = denseT + 1048576;          // 64 x 256
    int* counts  = (int*)(tailT + 16384);
    int* bsums   = counts + NN;
    int* excl    = bsums + 32;
    int* cursor  = excl + NN;
    // int pool inside dead hn region (20 MB):
    unsigned int* soff = (unsigned int*)hn;             // SOFF_LEN
    int* astart = (int*)(soff + SOFF_LEN);              // NN
    int* aendp  = astart + NN;                          // NN

    // CSR build (4-aligned, zero-padded, byte offsets)
    hipMemsetAsync(counts, 0, NN * sizeof(int), stream);
    hipMemsetAsync(soff, 0, SOFF_LEN * sizeof(int), stream);
    hist_kernel<<<(EE + 255) / 256, 256, 0, stream>>>(edges, counts, EE);
    scan_block<<<(NN + 1023) / 1024, 1024, 0, stream>>>(counts, excl, bsums, NN);
    scan_fix2<<<(NN + 255) / 256, 256, 0, stream>>>(excl, bsums, counts, astart, aendp, cursor, NN);
    scatter2<<<(EE + 255) / 256, 256, 0, stream>>>(edges, cursor, soff, EE);

    // weight prep
    transpose_bf16<<<dim3(8, 8, 1), 256, 0, stream>>>(head_W, headT, 256, 256, 0, 0);
    transpose_bf16<<<dim3(8, 8, 4), 256, 0, stream>>>(Wl, WzT, 256, 256, 65536, 131072);
    transpose_bf16<<<dim3(8, 8, 4), 256, 0, stream>>>(Wr, WzT + 65536, 256, 256, 65536, 131072);
    transpose_perm<<<dim3(32, 8, 4), 256, 0, stream>>>(dense_W, denseT, 256, 1024, 262144, 262144);
    transpose_bf16<<<dim3(2, 8, 1), 256, 0, stream>>>(tail_W, tailT, 256, 64, 0, 0);
    convert_bf16<<<(int)(NH / 4 + 255) / 256, 256, 0, stream>>>(x, hnb, (int)(NH / 4));

    const int GXP = 160;  // multiple of 8 -> XCD = bx & 7 for every by
    // head: xr = x @ head_W + head_b (fp32)
    gemm128<0><<<dim3(GXP, 2), 256, 0, stream>>>(hnb, headT, head_b, xr, NN, 256);

    for (int l = 0; l < 4; ++l) {
        if (l == 0)
            ln_kernel<<<NN / 4, 256, 0, stream>>>(xr, ng_g, ng_b, hnb, NN);
        else
            ln_dense<<<NN / 4, 256, 0, stream>>>(d_buf, xrb, ng_g + l * 256, ng_b + l * 256, hnb, NN);
        // [zl|zr] = hn @ [Wl|Wr]
        gemm128<1><<<dim3(GXP, 4), 256, 0, stream>>>(hnb, WzT + (size_t)l * 131072, nullptr, zb, NN, 512);
        // fused scores + plain-exp softmax agg + residual + LayerNorm (2 waves/node)
        gat_fused<<<NN, 128, 0, stream>>>(zb, att + l * 256, soff, astart, aendp, hnb,
                                          nd_g + l * 256, nd_b + l * 256, xrb, NN);
        // d = sum_c gelu(xr @ dense_W + dense_b) folded in-GEMM (N x 256 bf16) — clobbers zb (dead)
        gemm128<3><<<dim3(GXP, 8), 256, 0, stream>>>(xrb, denseT + (size_t)l * 262144,
                                                     dense_b + l * 1024, d_buf, NN, 1024);
    }
    // hb = bf16(d + xrb) -> hnb (dead); out = hb @ tail_W + tail_b
    combine_final<<<NN / 4, 256, 0, stream>>>(d_buf, xrb, hnb, NN);
    gemm128<0><<<dim3(GXP, 1), 256, 0, stream>>>(hnb, tailT, tail_b, out, NN, 64);
}